// Round 2
// 258.212 us; speedup vs baseline: 1.0264x; 1.0264x over previous
//
#include <hip/hip_runtime.h>

// ProtoNet scores, single-GEMM formulation:
//   Z = (X - mean) @ proj            (cols 0..255 of Y)
//   U = (X - mean) @ W, W = proj@P^T (cols 256..511 of Y)  [= Z@P^T exactly]
//   inv = 1/max(||Z||,eps); z2 = ||Z||^2 * inv^2
//   out[n][c] = -sqrt(max(z2 + ||p_c||^2 - 2*U[n][c]*inv, 0))
//
// R7: cooperative launch (R6) crashed the container -- grid.sync under the
// harness's graph capture is a hang. Same fusion goal, safe mechanism:
// merge prep1+prep2 into ONE plain kernel (161 blocks x 512 thr). The old
// prep1->prep2 dependency (mpart) is gone: block 160 computes mean@proj ->
// mean@W -> ||p||^2 by itself. Launch count 3 -> 2; prep W-blocks get 512
// threads (2x the old prep2 parallelism). Main kernel is byte-identical to
// the verified 93 us version.

#define DIN     1024
#define NPROTO  256
#define BM      128
#define ASTRIDE 40                       // ushorts/row: 32 k + 8 pad (16B-aligned)
#define KT_BYTES 32768                   // 512 cols * 32 k * 2 B per k-tile

// ws layout (bytes); total 1,051,648
#define BBLOB_OFF 0                      // 32 * 32768 = 1048576
#define MVEC_OFF  1048576                // 512 f32: [mean@proj | mean@W]
#define P2_OFF    1050624                // 256 f32

using bf16x8 = __attribute__((ext_vector_type(8))) short;
using f32x4  = __attribute__((ext_vector_type(4))) float;

struct BSet { bf16x8 v[8]; };

__device__ __forceinline__ unsigned f2bf(float f) {
  unsigned u = __float_as_uint(f);
  return (u + 0x7fffu + ((u >> 16) & 1u)) >> 16;
}

__device__ __forceinline__ uint2 pack4(float4 v) {
  return make_uint2(f2bf(v.x) | (f2bf(v.y) << 16), f2bf(v.z) | (f2bf(v.w) << 16));
}

// ---------------------------------------------------------------------------
// Merged prep: 161 blocks x 512 threads.
//   b 0..31   : pack proj k-tile kt=b into blob halves w=0,1
//   b 32..159 : W = proj @ P^T, pack into blob halves w=2,3 (kt=(b-32)>>2)
//   b 160     : mvec = [mean@proj | mean@(proj@P^T)] and p2 = ||p_c||^2
// ---------------------------------------------------------------------------
__global__ __launch_bounds__(512) void protonet_prep(
    const float* __restrict__ mean, const float* __restrict__ proj,
    const float* __restrict__ protos, unsigned* __restrict__ Bblob,
    float* __restrict__ mvec, float* __restrict__ p2g) {
  __shared__ __align__(16) char SM[37120];
  const int tid = threadIdx.x;
  const int b = blockIdx.x;

  if (b < 32) {
    // ---- proj half of B blob (w = 0,1), kt = b ----
    float* plds = (float*)SM;  // [32][257]
    const int kt = b;
    for (int i = 0; i < 16; ++i) {
      int idx = i * 512 + tid;
      int k = idx >> 8, n = idx & 255;
      plds[k * 257 + n] = proj[(kt * 32 + k) * 256 + n];
    }
    __syncthreads();
    for (int i = 0; i < 8; ++i) {
      int idx = i * 512 + tid;
      int j = idx & 3, lane = (idx >> 2) & 63, nt = (idx >> 8) & 7, w = idx >> 11;
      int l15 = lane & 15, q = lane >> 4;
      int col = w * 128 + nt * 16 + l15;
      int kk = q * 8 + 2 * j;
      unsigned lo = f2bf(plds[kk * 257 + col]);
      unsigned hi = f2bf(plds[(kk + 1) * 257 + col]);
      Bblob[((kt * 4 + w) * 8 + nt) * 256 + lane * 4 + j] = lo | (hi << 16);
    }
  } else if (b < 160) {
    // ---- W = proj @ P^T half of B blob (w = 2,3) ----
    float* plds = (float*)SM;                              // [32][256]
    unsigned short* Wl = (unsigned short*)(SM + 32768);    // [64][33]
    const int ib = b - 32, kt = ib >> 2, c0 = (ib & 3) * 64;
    for (int i = 0; i < 16; ++i) {
      int idx = i * 512 + tid;
      plds[idx] = proj[kt * 32 * 256 + idx];
    }
    __syncthreads();
    const int c = c0 + (tid & 63);
    const int wv = tid >> 6;  // 0..7, each owns 4 k-rows
    float acc4[4] = {0.f, 0.f, 0.f, 0.f};
    const float4* Pr = (const float4*)(protos + c * 256);
    for (int j4 = 0; j4 < 64; ++j4) {
      float4 pv = Pr[j4];
#pragma unroll
      for (int i = 0; i < 4; ++i) {
        const float4 pj = *(const float4*)&plds[(wv * 4 + i) * 256 + j4 * 4];
        acc4[i] += pj.x * pv.x + pj.y * pv.y + pj.z * pv.z + pj.w * pv.w;
      }
    }
#pragma unroll
    for (int i = 0; i < 4; ++i)
      Wl[(c - c0) * 33 + wv * 4 + i] = (unsigned short)f2bf(acc4[i]);
    __syncthreads();
    for (int i = 0; i < 2; ++i) {
      int idx = i * 512 + tid;
      int j = idx & 3, q = (idx >> 2) & 3, r = idx >> 4;
      int gc = c0 + r;
      int w = 2 + (gc >> 7);
      int cw = gc & 127;
      int nt = cw >> 4, l15 = cw & 15;
      int lane = q * 16 + l15;
      int kk = q * 8 + 2 * j;
      unsigned lo = Wl[r * 33 + kk], hi = Wl[r * 33 + kk + 1];
      Bblob[((kt * 4 + w) * 8 + nt) * 256 + lane * 4 + j] = lo | (hi << 16);
    }
  } else {
    // ---- mvec = [mean@proj | mean@W] and p2 = ||p_c||^2, single block ----
    float* meanl  = (float*)SM;            // 1024 f
    float* red    = (float*)(SM + 4096);   // 512 f
    float* red2   = (float*)(SM + 6144);   // 512 f
    float* mprojl = (float*)(SM + 8192);   // 256 f
    meanl[tid] = mean[tid];
    meanl[tid + 512] = mean[tid + 512];
    __syncthreads();
    {
      const int n = tid & 255, half = tid >> 8;
      float s = 0.f;
      const int k0 = half * 512;
#pragma unroll 8
      for (int k = k0; k < k0 + 512; ++k) s += meanl[k] * proj[k * 256 + n];
      red[tid] = s;
    }
    __syncthreads();
    if (tid < 256) {
      float m = red[tid] + red[tid + 256];
      mvec[tid] = m;
      mprojl[tid] = m;
    }
    __syncthreads();
    {
      const int c = tid & 255, half = tid >> 8;
      const float4* Pr = (const float4*)(protos + c * 256);
      float sw = 0.f, sp = 0.f;
      const int j0 = half * 32;
#pragma unroll 4
      for (int j4 = j0; j4 < j0 + 32; ++j4) {
        float4 pv = Pr[j4];
        const float4 mj = *(const float4*)&mprojl[j4 * 4];
        sw += mj.x * pv.x + mj.y * pv.y + mj.z * pv.z + mj.w * pv.w;
        sp += pv.x * pv.x + pv.y * pv.y + pv.z * pv.z + pv.w * pv.w;
      }
      red[tid] = sw;
      red2[tid] = sp;
    }
    __syncthreads();
    if (tid < 256) {
      mvec[256 + tid] = red[tid] + red[tid + 256];
      p2g[tid] = red2[tid] + red2[tid + 256];
    }
  }
}

// ---------------------------------------------------------------------------
// main: 256 blocks x 512 thr, BM=128 (byte-identical to verified 93 us R5).
// Wave (wr=wave>>2, wc=wave&3): rows [64*wr,+64), cols [128*wc,+128) of [Z|U].
// ---------------------------------------------------------------------------
__global__ __launch_bounds__(512, 2) void protonet_main(
    const float* __restrict__ X, const unsigned* __restrict__ Bblob,
    const float* __restrict__ mvec, const float* __restrict__ p2g,
    float* __restrict__ out) {
  __shared__ __align__(16) unsigned short Alds[2][BM * ASTRIDE];  // 2 x 10240 B
  __shared__ float rowsum[BM];
  __shared__ float rowinv[BM];
  __shared__ float rowz2[BM];

  const int tid = threadIdx.x;
  const int wave = tid >> 6;
  const int wc = wave & 3;               // column group
  const int wr = wave >> 2;              // row half
  const int lane = tid & 63;
  const int l15 = lane & 15;
  const int q = lane >> 4;
  const int row0 = blockIdx.x * BM;
  const int cn = wc * 128;
  const int rbase = wr * 64;

  if (tid < BM) rowsum[tid] = 0.f;

  const int ar = tid >> 3;               // 0..63
  const int ac4 = (tid & 7) * 4;
  const float* xb = X + (row0 + ar) * DIN + ac4;
  const char* Bb = (const char*)Bblob + wc * 8192 + lane * 16;

  f32x4 acc[4][8];
#pragma unroll
  for (int mt = 0; mt < 4; ++mt)
#pragma unroll
    for (int nt = 0; nt < 8; ++nt) acc[mt][nt] = (f32x4){0.f, 0.f, 0.f, 0.f};

  // ---- pipelined prologue: A(0) staged; X(1),X(2),B(0),B(1) in flight ----
  float4 t0 = *(const float4*)(xb);
  float4 t1 = *(const float4*)(xb + 64 * DIN);
  float4 xA0 = *(const float4*)(xb + 32);
  float4 xA1 = *(const float4*)(xb + 64 * DIN + 32);
  float4 xB0 = *(const float4*)(xb + 64);
  float4 xB1 = *(const float4*)(xb + 64 * DIN + 64);
  BSet BA, BB;
#pragma unroll
  for (int nt = 0; nt < 8; ++nt) BA.v[nt] = *(const bf16x8*)(Bb + nt * 1024);
#pragma unroll
  for (int nt = 0; nt < 8; ++nt)
    BB.v[nt] = *(const bf16x8*)(Bb + KT_BYTES + nt * 1024);
  *(uint2*)&Alds[0][ar * ASTRIDE + ac4] = pack4(t0);
  *(uint2*)&Alds[0][(ar + 64) * ASTRIDE + ac4] = pack4(t1);
  asm volatile("s_waitcnt lgkmcnt(0)\n\ts_barrier" ::: "memory");

  // one K-step; on entry xp holds X(kt+1), bs holds B(kt)
  auto step = [&](int kt, float4& xp0, float4& xp1, BSet& bs) {
    *(uint2*)&Alds[(kt + 1) & 1][ar * ASTRIDE + ac4] = pack4(xp0);
    *(uint2*)&Alds[(kt + 1) & 1][(ar + 64) * ASTRIDE + ac4] = pack4(xp1);
    int kx = kt + 3 <= 31 ? kt + 3 : 31;
    xp0 = *(const float4*)(xb + kx * 32);
    xp1 = *(const float4*)(xb + 64 * DIN + kx * 32);
    bf16x8 af[4];
#pragma unroll
    for (int mt = 0; mt < 4; ++mt)
      af[mt] =
          *(const bf16x8*)&Alds[kt & 1][(rbase + mt * 16 + l15) * ASTRIDE + q * 8];
#pragma unroll
    for (int mt = 0; mt < 4; ++mt)
#pragma unroll
      for (int nt = 0; nt < 8; ++nt)
        acc[mt][nt] = __builtin_amdgcn_mfma_f32_16x16x32_bf16(af[mt], bs.v[nt],
                                                              acc[mt][nt], 0, 0, 0);
    int kb = kt + 2 <= 31 ? kt + 2 : 31;
    const char* bsrc = Bb + kb * KT_BYTES;
#pragma unroll
    for (int nt = 0; nt < 8; ++nt) bs.v[nt] = *(const bf16x8*)(bsrc + nt * 1024);
    asm volatile("s_waitcnt lgkmcnt(0)\n\ts_barrier" ::: "memory");
  };

  for (int kt = 0; kt < 32; kt += 2) {
    step(kt, xA0, xA1, BA);
    step(kt + 1, xB0, xB1, BB);
  }

  // ---- epilogue: center, row norms (wc<2 waves hold Z), scores (wc>=2) ----
#pragma unroll
  for (int nt = 0; nt < 8; ++nt) {
    float mv = mvec[cn + nt * 16 + l15];
#pragma unroll
    for (int mt = 0; mt < 4; ++mt)
#pragma unroll
      for (int r = 0; r < 4; ++r) acc[mt][nt][r] -= mv;
  }

  if (wc < 2) {
#pragma unroll
    for (int mt = 0; mt < 4; ++mt)
#pragma unroll
      for (int r = 0; r < 4; ++r) {
        float ss = 0.f;
#pragma unroll
        for (int nt = 0; nt < 8; ++nt) ss += acc[mt][nt][r] * acc[mt][nt][r];
        ss += __shfl_xor(ss, 1);
        ss += __shfl_xor(ss, 2);
        ss += __shfl_xor(ss, 4);
        ss += __shfl_xor(ss, 8);
        if (l15 == 0) atomicAdd(&rowsum[rbase + mt * 16 + q * 4 + r], ss);
      }
  }
  __syncthreads();
  if (tid < BM) {
    float s = rowsum[tid];
    float inv = 1.0f / fmaxf(sqrtf(s), 1e-12f);
    rowinv[tid] = inv;
    rowz2[tid] = s * inv * inv;
  }
  __syncthreads();

  if (wc >= 2) {
#pragma unroll
    for (int nt = 0; nt < 8; ++nt) {
      int col = cn - 256 + nt * 16 + l15;
      float pp = p2g[col];
#pragma unroll
      for (int mt = 0; mt < 4; ++mt)
#pragma unroll
        for (int r = 0; r < 4; ++r) {
          int row = rbase + mt * 16 + q * 4 + r;
          float d2 = rowz2[row] + pp - 2.0f * acc[mt][nt][r] * rowinv[row];
          float sc = -sqrtf(fmaxf(d2, 0.f));
          __builtin_nontemporal_store(sc, &out[(row0 + row) * NPROTO + col]);
        }
    }
  }
}

extern "C" void kernel_launch(void* const* d_in, const int* in_sizes, int n_in,
                              void* d_out, int out_size, void* d_ws, size_t ws_size,
                              hipStream_t stream) {
  const float* X = (const float*)d_in[0];
  const float* mean = (const float*)d_in[1];
  const float* proj = (const float*)d_in[2];
  const float* protos = (const float*)d_in[3];
  float* out = (float*)d_out;

  char* ws = (char*)d_ws;  // uses 1,051,648 B
  unsigned* Bblob = (unsigned*)(ws + BBLOB_OFF);
  float* mvec = (float*)(ws + MVEC_OFF);
  float* p2 = (float*)(ws + P2_OFF);

  hipLaunchKernelGGL(protonet_prep, dim3(161), dim3(512), 0, stream,
                     mean, proj, protos, Bblob, mvec, p2);
  hipLaunchKernelGGL(protonet_main, dim3(256), dim3(512), 0, stream,
                     X, Bblob, mvec, p2, out);
}